// Round 1
// 297.253 us; speedup vs baseline: 1.0752x; 1.0752x over previous
//
#include <hip/hip_runtime.h>
#include <cstdint>
#include <cstddef>

typedef float f32x4 __attribute__((ext_vector_type(4)));
typedef long  lx2   __attribute__((ext_vector_type(2)));

#define PXB 1024   // partial-max blocks for x
#define PWB 64     // partial-max blocks for w
#define QWB 64     // quant blocks for w

// ---------------------------------------------------------------------------
// helpers
// ---------------------------------------------------------------------------
__device__ __forceinline__ void async_copy16(const uint8_t* g, uint8_t* s) {
    __builtin_amdgcn_global_load_lds(
        (const __attribute__((address_space(1))) void*)g,
        (__attribute__((address_space(3))) void*)s,
        16 /*bytes*/, 0 /*offset*/, 0 /*aux*/);
}

// block-wide max; every thread returns the result. Caller must not reuse
// scr until after a subsequent __syncthreads().
__device__ __forceinline__ float block_max(float m, float* scr) {
#pragma unroll
    for (int o = 32; o > 0; o >>= 1) m = fmaxf(m, __shfl_down(m, o, 64));
    const int lane = threadIdx.x & 63, wid = threadIdx.x >> 6;
    if (lane == 0) scr[wid] = m;
    __syncthreads();
    const int nw = blockDim.x >> 6;
    m = scr[0];
    for (int j = 1; j < nw; ++j) m = fmaxf(m, scr[j]);
    return m;
}

// ---------------------------------------------------------------------------
// 1. per-block amax partials (no atomics, no init kernel needed)
//    blocks [0,PXB) -> x, partials part[0..PXB); blocks [PXB,PXB+PWB) -> w
// ---------------------------------------------------------------------------
__global__ void amax_partials(const float4* __restrict__ x, int nx4,
                              const float4* __restrict__ w, int nw4,
                              float* __restrict__ part) {
    __shared__ float scr[8];
    const int b = blockIdx.x;
    const float4* p;
    int n4, nb, bi;
    if (b < PXB) { p = x; n4 = nx4; nb = PXB; bi = b; }
    else         { p = w; n4 = nw4; nb = PWB; bi = b - PXB; }
    float m = 0.0f;
    for (int i = bi * blockDim.x + threadIdx.x; i < n4; i += nb * blockDim.x) {
        float4 v = p[i];
        m = fmaxf(m, fmaxf(fmaxf(fabsf(v.x), fabsf(v.y)),
                           fmaxf(fabsf(v.z), fabsf(v.w))));
    }
    m = block_max(m, scr);
    if (threadIdx.x == 0) part[b] = m;
}

// ---------------------------------------------------------------------------
// 2. quantize w only (tiny: 4 MB read, 1 MB write). x is quantized inside
//    the GEMM now -- w is quantized once here because all 256 M-panels
//    reuse it (converting in-GEMM would redo the work 256x).
// ---------------------------------------------------------------------------
__global__ void quant_w_kernel(const float4* __restrict__ w, int nw16,
                               const float* __restrict__ part,
                               int4* __restrict__ wq) {
    __shared__ float scr[8];
    float m = 0.0f;
    for (int i = threadIdx.x; i < PWB; i += blockDim.x)
        m = fmaxf(m, part[PXB + i]);
    m = block_max(m, scr);
    const float r = 1.0f / fmaxf(m / 448.0f, 1e-12f);

    for (int i = blockIdx.x * blockDim.x + threadIdx.x; i < nw16;
         i += QWB * blockDim.x) {
        int4 o;
#pragma unroll
        for (int j = 0; j < 4; ++j) {
            float4 v = w[i * 4 + j];
            int p = 0;
            p = __builtin_amdgcn_cvt_pk_fp8_f32(v.x * r, v.y * r, p, false);
            p = __builtin_amdgcn_cvt_pk_fp8_f32(v.z * r, v.w * r, p, true);
            ((int*)&o)[j] = p;
        }
        wq[i] = o;
    }
}

// ---------------------------------------------------------------------------
// 3. fp8 GEMM with fused x-quantization:
//    C[m,n] = (sum_k q(A32[m,k]) * B[n,k]) * scale + bias[n]
//    128x128 tile, BK=64, 256 thr (4 waves 2x2, each 64x64 via 4x4 MFMA tiles)
//    A is read as fp32 and converted to fp8 in registers during staging --
//    byte-identical values and byte-identical LDS layout to the previous
//    pre-quantized path, so fragments/MFMA/epilogue are unchanged.
//    Fragment K-permutation: frag(quad,ks) = row bytes [quad*16 + ks*8, +8).
//    Valid because A and B share the same K permutation.
// ---------------------------------------------------------------------------
__global__ __launch_bounds__(256) void gemm_fp8_kernel(
    const float* __restrict__ A32,   // [M][K] fp32 (x)
    const uint8_t* __restrict__ B,   // [N][K] fp8 (w)
    const float* __restrict__ bias,  // [N]
    const float* __restrict__ part,  // amax partials
    float* __restrict__ out,         // [M][N] fp32
    int M, int N, int K) {
    __shared__ long lds64[2048];     // 16 KiB: A tile [128][64B] + B tile
    uint8_t* Abase = (uint8_t*)lds64;
    uint8_t* Bbase = Abase + 8192;

    const int tid  = threadIdx.x;
    const int l    = tid & 63;
    const int w    = tid >> 6;
    const int lm   = l & 15;
    const int quad = l >> 4;
    const int wm   = (w >> 1) * 64;  // wave's M offset in tile
    const int wn   = (w & 1) * 64;   // wave's N offset in tile

    // XCD-aware swizzle: linear id = bx + 8*by, HW round-robins XCD by id%8.
    // Default order puts the 8 blocks sharing an A panel on 8 DIFFERENT XCDs
    // (measured: 133 MB fetch vs 33.5 MB minimum). Remap so a panel's 8
    // blocks have consecutive ids with equal id%8 -> same XCD, A panel hits
    // that XCD's L2. Bijective for the 8x256 grid.
    int bx = blockIdx.x, by = blockIdx.y;
    if (gridDim.x == 8) {
        const int lin = blockIdx.x + (blockIdx.y << 3);
        const int c = lin & 7;        // physical XCD
        const int k = lin >> 3;       // 0..gridDim.y-1
        bx = k & 7;
        by = (k & ~7) | c;
    }
    const size_t am0 = (size_t)by * 128;
    const size_t bn0 = (size_t)bx * 128;

    // A staging geometry: thread t owns 4 fp8 bytes per row, 8 rows/K-step.
    const int arow = tid >> 4;          // 0..15 (row within 16-row group)
    const int acol = (tid & 15) * 4;    // K offset (floats) within 64
    const float* aptr = A32 + (am0 + arow) * (size_t)K + acol;

    // prologue A loads issued first: HBM latency overlaps the partials
    // reduction below.
    f32x4 av[8];
#pragma unroll
    for (int j = 0; j < 8; ++j)
        av[j] = *(const f32x4*)(aptr + (size_t)j * 16 * K);

    // per-tensor scales from partials (cheap block-local reduction)
    float* scr = (float*)lds64;
    float mx = 0.0f, mw = 0.0f;
    for (int i = tid; i < PXB; i += 256) mx = fmaxf(mx, part[i]);
    for (int i = tid; i < PWB; i += 256) mw = fmaxf(mw, part[PXB + i]);
    mx = block_max(mx, scr);
    mw = block_max(mw, scr + 8);
    const float sx = fmaxf(mx / 448.0f, 1e-12f);
    const float sw = fmaxf(mw / 448.0f, 1e-12f);
    const float scale = sx * sw;
    const float rq = 1.0f / sx;      // x quant multiplier (matches reference)
    __syncthreads();  // scr reads done before staging overwrites LDS

    f32x4 acc[4][4];
#pragma unroll
    for (int i = 0; i < 4; ++i)
#pragma unroll
        for (int j = 0; j < 4; ++j) acc[i][j] = (f32x4)0.0f;

    const int slot0 = w * 64 + l;  // 0..255; slot s -> row s/4, 16B-chunk s%4

    for (int kt = 0; kt < K; kt += 64) {
        // B: async global->LDS (fp8, tiny, L2-resident)
#pragma unroll
        for (int i = 0; i < 2; ++i) {
            const int s    = i * 256 + slot0;
            const int row  = s >> 2;
            const int chnk = s & 3;
            async_copy16(B + (bn0 + row) * K + kt + chnk * 16,
                         Bbase + (i * 4 + w) * 1024);
        }
        // A: convert this K-step's prefetched fp32 regs -> fp8, write LDS.
        // Layout matches old global_load_lds layout byte-for-byte:
        // row-major [128 rows][64 bytes]. ds_write_b32 banks are 2-way
        // aliased across the wave (free).
#pragma unroll
        for (int j = 0; j < 8; ++j) {
            int p = 0;
            p = __builtin_amdgcn_cvt_pk_fp8_f32(av[j].x * rq, av[j].y * rq, p, false);
            p = __builtin_amdgcn_cvt_pk_fp8_f32(av[j].z * rq, av[j].w * rq, p, true);
            *(int*)(Abase + (j * 16 + arow) * 64 + acol) = p;
        }
        __syncthreads();

        lx2 a[4], b[4];
#pragma unroll
        for (int t = 0; t < 4; ++t) {
            a[t] = *(const lx2*)&lds64[(wm + t * 16 + lm) * 8 + quad * 2];
            b[t] = *(const lx2*)&lds64[1024 + (wn + t * 16 + lm) * 8 + quad * 2];
        }
        // prefetch next K-step's A (overlaps the MFMA phase; drained at the
        // trailing barrier, by which point MFMA has covered most latency)
        if (kt + 64 < K) {
            const float* ap = aptr + (kt + 64);
#pragma unroll
            for (int j = 0; j < 8; ++j)
                av[j] = *(const f32x4*)(ap + (size_t)j * 16 * K);
        }
#pragma unroll
        for (int ks = 0; ks < 2; ++ks)
#pragma unroll
            for (int mt = 0; mt < 4; ++mt)
#pragma unroll
                for (int nt = 0; nt < 4; ++nt)
                    acc[mt][nt] = __builtin_amdgcn_mfma_f32_16x16x32_fp8_fp8(
                        a[mt][ks], b[nt][ks], acc[mt][nt], 0, 0, 0);
        __syncthreads();
    }

    // epilogue: D row = quad*4+reg, col = lm (within each 16x16 tile)
#pragma unroll
    for (int nt = 0; nt < 4; ++nt) {
        const int n = (int)bn0 + wn + nt * 16 + lm;
        const float bv = bias[n];
#pragma unroll
        for (int mt = 0; mt < 4; ++mt) {
            const size_t mrow = am0 + wm + mt * 16 + quad * 4;
#pragma unroll
            for (int r = 0; r < 4; ++r) {
                out[(mrow + r) * (size_t)N + n] = acc[mt][nt][r] * scale + bv;
            }
        }
    }
}

// ---------------------------------------------------------------------------
// host launcher
// ---------------------------------------------------------------------------
extern "C" void kernel_launch(void* const* d_in, const int* in_sizes, int n_in,
                              void* d_out, int out_size, void* d_ws,
                              size_t ws_size, hipStream_t stream) {
    const float* x      = (const float*)d_in[0];
    const float* weight = (const float*)d_in[1];
    const float* bias   = (const float*)d_in[2];
    float* out          = (float*)d_out;

    const int nx = in_sizes[0];        // M*K = 33554432
    const int nw = in_sizes[1];        // N*K = 1048576
    const int N  = in_sizes[2];        // 1024
    const int K  = nw / N;             // 1024
    const int M  = nx / K;             // 32768

    float* part     = (float*)d_ws;                 // PXB+PWB floats
    uint8_t* w_fp8  = (uint8_t*)d_ws + 8192;        // N*K fp8

    amax_partials<<<PXB + PWB, 256, 0, stream>>>(
        (const float4*)x, nx / 4, (const float4*)weight, nw / 4, part);
    quant_w_kernel<<<QWB, 256, 0, stream>>>(
        (const float4*)weight, nw / 16, part, (int4*)w_fp8);
    gemm_fp8_kernel<<<dim3(N / 128, M / 128), 256, 0, stream>>>(
        x, w_fp8, bias, part, out, M, N, K);
}